// Round 1
// baseline (353.081 us; speedup 1.0000x reference)
//
#include <hip/hip_runtime.h>

// Problem constants
#define BATCH    2048
#define FLAT_IN  512
#define PROJ_DIM 256
#define HEADS    16384
#define ACT_DIM  64

#define TILE_M 64
#define TILE_N 64
#define TILE_K 32
#define PAD_T  76   // leading dim (floats) for transposed [k][row] tiles; 76*4B=304B, 16B-aligned, 4-way max write conflict
#define PAD_B  68   // leading dim for direct [k][n] B tile; 16B-aligned

#define HC      1024              // heads per block chunk
#define NCHUNK  (HEADS / HC)      // 16

// ---------------------------------------------------------------------------
// Kernel 1: C[M,N] = A[M,K] @ B[K,N], all fp32 row-major.
// grid (M/64, N/64), block 256 (16x16 logical), 4x4 per thread.
// ---------------------------------------------------------------------------
__global__ __launch_bounds__(256) void gemm_proj(
    const float* __restrict__ A, const float* __restrict__ B,
    float* __restrict__ C, int M, int N, int K)
{
  __shared__ float a_t[TILE_K][PAD_T]; // transposed: [k][m]
  __shared__ float b_t[TILE_K][PAD_B]; // direct:     [k][n]
  const int tid = threadIdx.x;
  const int tx = tid & 15, ty = tid >> 4;
  const int m0 = blockIdx.x * TILE_M, n0 = blockIdx.y * TILE_N;

  float acc[4][4] = {};

  for (int k0 = 0; k0 < K; k0 += TILE_K) {
    // stage A (64 rows x 32 k), transposed into LDS
#pragma unroll
    for (int it = 0; it < 2; ++it) {
      int idx = tid + it * 256;       // 0..511
      int row = idx >> 3;             // 0..63
      int kq  = idx & 7;              // 0..7  (float4 quads along k)
      float4 f = *(const float4*)(A + (size_t)(m0 + row) * K + k0 + kq * 4);
      a_t[kq * 4 + 0][row] = f.x;
      a_t[kq * 4 + 1][row] = f.y;
      a_t[kq * 4 + 2][row] = f.z;
      a_t[kq * 4 + 3][row] = f.w;
    }
    // stage B (32 k x 64 n), already K-major
#pragma unroll
    for (int it = 0; it < 2; ++it) {
      int idx = tid + it * 256;
      int k  = idx >> 4;              // 0..31
      int cq = idx & 15;              // 0..15
      *(float4*)&b_t[k][cq * 4] =
          *(const float4*)(B + (size_t)(k0 + k) * N + n0 + cq * 4);
    }
    __syncthreads();
#pragma unroll
    for (int k = 0; k < TILE_K; ++k) {
      float4 av = *(const float4*)&a_t[k][ty * 4];
      float4 bv = *(const float4*)&b_t[k][tx * 4];
      float a[4] = {av.x, av.y, av.z, av.w};
      float b[4] = {bv.x, bv.y, bv.z, bv.w};
#pragma unroll
      for (int i = 0; i < 4; ++i)
#pragma unroll
        for (int j = 0; j < 4; ++j)
          acc[i][j] = fmaf(a[i], b[j], acc[i][j]);
    }
    __syncthreads();
  }

#pragma unroll
  for (int i = 0; i < 4; ++i) {
    float4 v = make_float4(acc[i][0], acc[i][1], acc[i][2], acc[i][3]);
    *(float4*)(C + (size_t)(m0 + ty * 4 + i) * N + n0 + tx * 4) = v;
  }
}

// ---------------------------------------------------------------------------
// Kernel 2: similarities = S[B,256] @ Mem[H,256]^T, fused running argmax.
// grid (B/64, HEADS/HC), block 256. Writes per-(row,chunk) partial (max, idx).
// ---------------------------------------------------------------------------
__global__ __launch_bounds__(256) void sim_argmax(
    const float* __restrict__ S, const float* __restrict__ Mem,
    float* __restrict__ pmax, int* __restrict__ pidx)
{
  __shared__ float a_t[TILE_K][PAD_T]; // [k][row]   (S tile, transposed)
  __shared__ float b_t[TILE_K][PAD_T]; // [k][head]  (Mem tile, transposed)
  __shared__ float red_max[TILE_M][16];
  __shared__ int   red_idx[TILE_M][16];

  const int tid = threadIdx.x;
  const int tx = tid & 15, ty = tid >> 4;
  const int m0 = blockIdx.x * TILE_M;
  const int h0 = blockIdx.y * HC;

  float rmax[4] = {-3.4e38f, -3.4e38f, -3.4e38f, -3.4e38f};
  int   ridx[4] = {0, 0, 0, 0};

  for (int hs = 0; hs < HC; hs += TILE_N) {
    float acc[4][4] = {};
    for (int k0 = 0; k0 < PROJ_DIM; k0 += TILE_K) {
#pragma unroll
      for (int it = 0; it < 2; ++it) {
        int idx = tid + it * 256;
        int row = idx >> 3;           // 0..63
        int kq  = idx & 7;
        float4 f = *(const float4*)(S + (size_t)(m0 + row) * PROJ_DIM + k0 + kq * 4);
        a_t[kq * 4 + 0][row] = f.x;
        a_t[kq * 4 + 1][row] = f.y;
        a_t[kq * 4 + 2][row] = f.z;
        a_t[kq * 4 + 3][row] = f.w;
        float4 g = *(const float4*)(Mem + (size_t)(h0 + hs + row) * PROJ_DIM + k0 + kq * 4);
        b_t[kq * 4 + 0][row] = g.x;
        b_t[kq * 4 + 1][row] = g.y;
        b_t[kq * 4 + 2][row] = g.z;
        b_t[kq * 4 + 3][row] = g.w;
      }
      __syncthreads();
#pragma unroll
      for (int k = 0; k < TILE_K; ++k) {
        float4 av = *(const float4*)&a_t[k][ty * 4];
        float4 bv = *(const float4*)&b_t[k][tx * 4];
        float a[4] = {av.x, av.y, av.z, av.w};
        float b[4] = {bv.x, bv.y, bv.z, bv.w};
#pragma unroll
        for (int i = 0; i < 4; ++i)
#pragma unroll
          for (int j = 0; j < 4; ++j)
            acc[i][j] = fmaf(a[i], b[j], acc[i][j]);
      }
      __syncthreads();
    }
    // running argmax update (ascending head order + strict '>' keeps first max)
#pragma unroll
    for (int j = 0; j < 4; ++j) {
      int h = h0 + hs + tx * 4 + j;
#pragma unroll
      for (int i = 0; i < 4; ++i) {
        if (acc[i][j] > rmax[i]) { rmax[i] = acc[i][j]; ridx[i] = h; }
      }
    }
  }

  // reduce across the 16 tx-threads sharing each row
#pragma unroll
  for (int i = 0; i < 4; ++i) {
    red_max[ty * 4 + i][tx] = rmax[i];
    red_idx[ty * 4 + i][tx] = ridx[i];
  }
  __syncthreads();
  if (tid < TILE_M) {
    int row = tid;
    float best = -3.4e38f; int bidx = 0;
#pragma unroll
    for (int t = 0; t < 16; ++t) {
      float v = red_max[row][t];
      if (v > best) { best = v; bidx = red_idx[row][t]; }
    }
    pmax[(size_t)(m0 + row) * NCHUNK + blockIdx.y] = best;
    pidx[(size_t)(m0 + row) * NCHUNK + blockIdx.y] = bidx;
  }
}

// ---------------------------------------------------------------------------
// Kernel 3: final reduce over chunks + gather logits row.
// grid (BATCH), block 64. All 64 lanes redundantly reduce (cached scalar loads).
// ---------------------------------------------------------------------------
__global__ __launch_bounds__(64) void gather_out(
    const float* __restrict__ pmax, const int* __restrict__ pidx,
    const float* __restrict__ logits, float* __restrict__ out)
{
  const int row = blockIdx.x;
  float best = -3.4e38f; int bidx = 0;
#pragma unroll
  for (int c = 0; c < NCHUNK; ++c) {
    float v = pmax[(size_t)row * NCHUNK + c];
    if (v > best) { best = v; bidx = pidx[(size_t)row * NCHUNK + c]; }
  }
  out[(size_t)row * ACT_DIM + threadIdx.x] =
      logits[(size_t)bidx * ACT_DIM + threadIdx.x];
}

// ---------------------------------------------------------------------------
extern "C" void kernel_launch(void* const* d_in, const int* in_sizes, int n_in,
                              void* d_out, int out_size, void* d_ws, size_t ws_size,
                              hipStream_t stream) {
  const float* state  = (const float*)d_in[0]; // [2048, 512]
  const float* rp     = (const float*)d_in[1]; // [512, 256]
  const float* mem    = (const float*)d_in[2]; // [16384, 256]
  const float* logits = (const float*)d_in[3]; // [16384, 64]
  float* out = (float*)d_out;                  // [2048, 64]

  float* s    = (float*)d_ws;                          // 2048*256 fp32 = 2 MB
  float* pmax = s + (size_t)BATCH * PROJ_DIM;          // 2048*16
  int*   pidx = (int*)(pmax + (size_t)BATCH * NCHUNK); // 2048*16

  dim3 g1(BATCH / TILE_M, PROJ_DIM / TILE_N);          // (32, 4)
  gemm_proj<<<g1, 256, 0, stream>>>(state, rp, s, BATCH, PROJ_DIM, FLAT_IN);

  dim3 g2(BATCH / TILE_M, NCHUNK);                     // (32, 16)
  sim_argmax<<<g2, 256, 0, stream>>>(s, mem, pmax, pidx);

  gather_out<<<BATCH, ACT_DIM, 0, stream>>>(pmax, pidx, logits, out);
}

// Round 2
// 218.133 us; speedup vs baseline: 1.6186x; 1.6186x over previous
//
#include <hip/hip_runtime.h>

// Problem constants
#define BATCH    2048
#define FLAT_IN  512
#define PROJ_DIM 256
#define HEADS    16384
#define ACT_DIM  64

typedef __attribute__((ext_vector_type(8))) short short8;   // 8 bf16 = 4 VGPR
typedef __attribute__((ext_vector_type(4))) float floatx4;  // MFMA C/D

// round-to-nearest-even fp32 -> bf16 (bits)
__device__ __forceinline__ unsigned short f2bf(float x) {
  unsigned u = __float_as_uint(x);
  u += 0x7fff + ((u >> 16) & 1);
  return (unsigned short)(u >> 16);
}
__device__ __forceinline__ float bf2f(unsigned short b) {
  return __uint_as_float(((unsigned)b) << 16);
}

__device__ __forceinline__ void top2_ins(float v, int h, float& b1, int& i1,
                                         float& b2, int& i2) {
  if (v > b1 || (v == b1 && h < i1)) { b2 = b1; i2 = i1; b1 = v; i1 = h; }
  else if (v > b2 || (v == b2 && h < i2)) { b2 = v; i2 = h; }
}

// ---------------------------------------------------------------------------
// Kernel 1: s = state @ rp (fp32 VALU), epilogue also emits bf16 hi/mid splits.
// grid (2048/64, 256/64), block 256, 4x4 per thread. (same as round-1, passed)
// ---------------------------------------------------------------------------
#define TILE_M 64
#define TILE_N 64
#define TILE_K 32
#define PAD_T  76
#define PAD_B  68

__global__ __launch_bounds__(256) void gemm_proj(
    const float* __restrict__ A, const float* __restrict__ B,
    float* __restrict__ C, unsigned short* __restrict__ Chi,
    unsigned short* __restrict__ Cmid, int M, int N, int K)
{
  __shared__ float a_t[TILE_K][PAD_T];
  __shared__ float b_t[TILE_K][PAD_B];
  const int tid = threadIdx.x;
  const int tx = tid & 15, ty = tid >> 4;
  const int m0 = blockIdx.x * TILE_M, n0 = blockIdx.y * TILE_N;

  float acc[4][4] = {};

  for (int k0 = 0; k0 < K; k0 += TILE_K) {
#pragma unroll
    for (int it = 0; it < 2; ++it) {
      int idx = tid + it * 256;
      int row = idx >> 3;
      int kq  = idx & 7;
      float4 f = *(const float4*)(A + (size_t)(m0 + row) * K + k0 + kq * 4);
      a_t[kq * 4 + 0][row] = f.x;
      a_t[kq * 4 + 1][row] = f.y;
      a_t[kq * 4 + 2][row] = f.z;
      a_t[kq * 4 + 3][row] = f.w;
    }
#pragma unroll
    for (int it = 0; it < 2; ++it) {
      int idx = tid + it * 256;
      int k  = idx >> 4;
      int cq = idx & 15;
      *(float4*)&b_t[k][cq * 4] =
          *(const float4*)(B + (size_t)(k0 + k) * N + n0 + cq * 4);
    }
    __syncthreads();
#pragma unroll
    for (int k = 0; k < TILE_K; ++k) {
      float4 av = *(const float4*)&a_t[k][ty * 4];
      float4 bv = *(const float4*)&b_t[k][tx * 4];
      float a[4] = {av.x, av.y, av.z, av.w};
      float b[4] = {bv.x, bv.y, bv.z, bv.w};
#pragma unroll
      for (int i = 0; i < 4; ++i)
#pragma unroll
        for (int j = 0; j < 4; ++j)
          acc[i][j] = fmaf(a[i], b[j], acc[i][j]);
    }
    __syncthreads();
  }

#pragma unroll
  for (int i = 0; i < 4; ++i) {
    int row = m0 + ty * 4 + i, colo = n0 + tx * 4;
    float4 v = make_float4(acc[i][0], acc[i][1], acc[i][2], acc[i][3]);
    *(float4*)(C + (size_t)row * N + colo) = v;
    ushort4 h, m;
    h.x = f2bf(v.x); m.x = f2bf(v.x - bf2f(h.x));
    h.y = f2bf(v.y); m.y = f2bf(v.y - bf2f(h.y));
    h.z = f2bf(v.z); m.z = f2bf(v.z - bf2f(h.z));
    h.w = f2bf(v.w); m.w = f2bf(v.w - bf2f(h.w));
    *(ushort4*)(Chi  + (size_t)row * N + colo) = h;
    *(ushort4*)(Cmid + (size_t)row * N + colo) = m;
  }
}

// ---------------------------------------------------------------------------
// Kernel 2: elementwise bf16 hi/mid split of memories. 4 floats/thread.
// ---------------------------------------------------------------------------
__global__ __launch_bounds__(256) void split_mem(
    const float* __restrict__ in, unsigned short* __restrict__ hi,
    unsigned short* __restrict__ mid)
{
  int i = blockIdx.x * 256 + threadIdx.x;       // float4 index
  float4 v = ((const float4*)in)[i];
  ushort4 h, m;
  h.x = f2bf(v.x); m.x = f2bf(v.x - bf2f(h.x));
  h.y = f2bf(v.y); m.y = f2bf(v.y - bf2f(h.y));
  h.z = f2bf(v.z); m.z = f2bf(v.z - bf2f(h.z));
  h.w = f2bf(v.w); m.w = f2bf(v.w - bf2f(h.w));
  ((ushort4*)hi)[i]  = h;
  ((ushort4*)mid)[i] = m;
}

// ---------------------------------------------------------------------------
// Kernel 3: approximate sims via split-bf16 MFMA (hi*hi + hi*mid + mid*hi),
// fused per-block top-2 per row. 128x128 tile, BK=32, global_load_lds(16B).
// grid (16 rowblocks, 128 headchunks), block 256 (4 waves, 2x2 of 64x64).
// partial[row][chunk] = {v1, h1, v2, h2}
// ---------------------------------------------------------------------------
#define GLDS16(g, l)                                                          \
  __builtin_amdgcn_global_load_lds(                                           \
      (__attribute__((address_space(1))) void*)(void*)(g),                    \
      (__attribute__((address_space(3))) void*)(l), 16, 0, 0)

__global__ __launch_bounds__(256) void sim_topk(
    const unsigned short* __restrict__ Ahi, const unsigned short* __restrict__ Amid,
    const unsigned short* __restrict__ Bhi, const unsigned short* __restrict__ Bmid,
    floatx4* __restrict__ partial)
{
  __shared__ __align__(16) char smem[32768];
  unsigned short* sAhi  = (unsigned short*)smem;        // [128][32] bf16, 8KB
  unsigned short* sAmid = sAhi + 4096;
  unsigned short* sBhi  = sAmid + 4096;
  unsigned short* sBmid = sBhi + 4096;

  const int tid  = threadIdx.x;
  const int lane = tid & 63;
  const int w    = tid >> 6;
  const int quad = lane >> 4;
  const int col  = lane & 15;
  const int wm   = (w >> 1) * 64;
  const int wn   = (w & 1) * 64;

  const int m0 = blockIdx.x * 128;   // batch rows
  const int h0 = blockIdx.y * 128;   // heads

  floatx4 acc[4][4];
#pragma unroll
  for (int i = 0; i < 4; ++i)
#pragma unroll
    for (int j = 0; j < 4; ++j) {
      acc[i][j][0] = 0.f; acc[i][j][1] = 0.f;
      acc[i][j][2] = 0.f; acc[i][j][3] = 0.f;
    }

  // staging geometry: lin in [0,512), r = lin>>2 (tile row), seg = lin&3
  // (8 bf16 per 16B load); LDS layout = [r][k] row-major, 32 bf16 per row.
  const int lin0 = tid, lin1 = tid + 256;
  const int r0 = lin0 >> 2, s0 = lin0 & 3;
  const int r1 = lin1 >> 2, s1 = lin1 & 3;

  const unsigned short* gAhi  = Ahi  + (size_t)m0 * PROJ_DIM;
  const unsigned short* gAmid = Amid + (size_t)m0 * PROJ_DIM;
  const unsigned short* gBhi  = Bhi  + (size_t)h0 * PROJ_DIM;
  const unsigned short* gBmid = Bmid + (size_t)h0 * PROJ_DIM;

  for (int kc = 0; kc < PROJ_DIM; kc += 32) {
    // issue async global->LDS (width 16) for 4 planes x 2 halves
    {
      size_t go0 = (size_t)r0 * PROJ_DIM + kc + s0 * 8;
      size_t go1 = (size_t)r1 * PROJ_DIM + kc + s1 * 8;
      GLDS16(gAhi  + go0, sAhi  + lin0 * 8);
      GLDS16(gAhi  + go1, sAhi  + lin1 * 8);
      GLDS16(gAmid + go0, sAmid + lin0 * 8);
      GLDS16(gAmid + go1, sAmid + lin1 * 8);
      GLDS16(gBhi  + go0, sBhi  + lin0 * 8);
      GLDS16(gBhi  + go1, sBhi  + lin1 * 8);
      GLDS16(gBmid + go0, sBmid + lin0 * 8);
      GLDS16(gBmid + go1, sBmid + lin1 * 8);
    }
    __syncthreads();   // drains vmcnt(0) then barrier

    short8 fahi[4], famid[4], fbhi[4], fbmid[4];
#pragma unroll
    for (int i = 0; i < 4; ++i) {
      int off = (wm + i * 16 + col) * 32 + quad * 8;
      fahi[i]  = *(const short8*)(sAhi  + off);
      famid[i] = *(const short8*)(sAmid + off);
    }
#pragma unroll
    for (int j = 0; j < 4; ++j) {
      int off = (wn + j * 16 + col) * 32 + quad * 8;
      fbhi[j]  = *(const short8*)(sBhi  + off);
      fbmid[j] = *(const short8*)(sBmid + off);
    }
#pragma unroll
    for (int i = 0; i < 4; ++i)
#pragma unroll
      for (int j = 0; j < 4; ++j) {
        acc[i][j] = __builtin_amdgcn_mfma_f32_16x16x32_bf16(fahi[i],  fbhi[j],  acc[i][j], 0, 0, 0);
        acc[i][j] = __builtin_amdgcn_mfma_f32_16x16x32_bf16(fahi[i],  fbmid[j], acc[i][j], 0, 0, 0);
        acc[i][j] = __builtin_amdgcn_mfma_f32_16x16x32_bf16(famid[i], fbhi[j],  acc[i][j], 0, 0, 0);
      }
    __syncthreads();   // all waves done reading before next chunk overwrites
  }

  // ---- epilogue: per (row) top-2 over this block's 128 heads ----
  // reuse staging LDS as candidate buffers
  float* cv = (float*)smem;                 // [128][32]
  int*   ch = (int*)(smem + 16384);         // [128][32]

#pragma unroll
  for (int i = 0; i < 4; ++i)
#pragma unroll
    for (int r = 0; r < 4; ++r) {
      float v0 = acc[i][0][r], v1 = acc[i][1][r];
      float v2 = acc[i][2][r], v3 = acc[i][3][r];
      float m01 = fmaxf(v0, v1); int j01 = (v1 > v0) ? 1 : 0;
      float m23 = fmaxf(v2, v3); int j23 = (v3 > v2) ? 3 : 2;
      float mv  = fmaxf(m01, m23); int jb = (m23 > m01) ? j23 : j01;
      int row  = wm + i * 16 + quad * 4 + r;          // 0..127
      int slot = (w & 1) * 16 + col;                  // 0..31
      cv[row * 32 + slot] = mv;
      ch[row * 32 + slot] = h0 + wn + jb * 16 + col;  // absolute head
    }
  __syncthreads();

  if (tid < 128) {
    int row = tid;
    float b1 = -3.4e38f, b2 = -3.4e38f; int i1 = 0x7fffffff, i2 = 0x7fffffff;
#pragma unroll 8
    for (int s = 0; s < 32; ++s) {
      top2_ins(cv[row * 32 + s], ch[row * 32 + s], b1, i1, b2, i2);
    }
    floatx4 p;
    p[0] = b1; p[1] = __int_as_float(i1);
    p[2] = b2; p[3] = __int_as_float(i2);
    partial[(size_t)(m0 + row) * 128 + blockIdx.y] = p;
  }
}

// ---------------------------------------------------------------------------
// Kernel 4: merge 128 chunk-partials -> global top-2, exact fp32 rescore of
// both candidates, pick winner, gather logits row. 1 wave per batch row.
// ---------------------------------------------------------------------------
__global__ __launch_bounds__(64) void finalize(
    const floatx4* __restrict__ partial, const float* __restrict__ S,
    const float* __restrict__ Mem, const float* __restrict__ logits,
    float* __restrict__ out)
{
  const int row  = blockIdx.x;
  const int lane = threadIdx.x;

  float b1 = -3.4e38f, b2 = -3.4e38f; int i1 = 0x7fffffff, i2 = 0x7fffffff;
#pragma unroll
  for (int t = 0; t < 2; ++t) {
    floatx4 p = partial[(size_t)row * 128 + lane * 2 + t];
    top2_ins(p[0], __float_as_int(p[1]), b1, i1, b2, i2);
    top2_ins(p[2], __float_as_int(p[3]), b1, i1, b2, i2);
  }

  // global top-1 across wave
  float g1 = b1; int gi1 = i1;
#pragma unroll
  for (int d = 32; d; d >>= 1) {
    float ov = __shfl_xor(g1, d); int oi = __shfl_xor(gi1, d);
    if (ov > g1 || (ov == g1 && oi < gi1)) { g1 = ov; gi1 = oi; }
  }
  // global top-2: best candidate excluding gi1
  float c  = (i1 == gi1) ? b2 : b1;
  int   ci = (i1 == gi1) ? i2 : i1;
  float g2 = c; int gi2 = ci;
#pragma unroll
  for (int d = 32; d; d >>= 1) {
    float ov = __shfl_xor(g2, d); int oi = __shfl_xor(gi2, d);
    if (ov > g2 || (ov == g2 && oi < gi2)) { g2 = ov; gi2 = oi; }
  }

  // exact fp32 rescore of the two candidate heads
  float4 sv = ((const float4*)(S   + (size_t)row * PROJ_DIM))[lane];
  float4 m1 = ((const float4*)(Mem + (size_t)gi1 * PROJ_DIM))[lane];
  float4 m2 = ((const float4*)(Mem + (size_t)gi2 * PROJ_DIM))[lane];
  float d1 = sv.x * m1.x + sv.y * m1.y + sv.z * m1.z + sv.w * m1.w;
  float d2 = sv.x * m2.x + sv.y * m2.y + sv.z * m2.z + sv.w * m2.w;
#pragma unroll
  for (int d = 32; d; d >>= 1) {
    d1 += __shfl_xor(d1, d);
    d2 += __shfl_xor(d2, d);
  }
  int win = (d2 > d1 || (d1 == d2 && gi2 < gi1)) ? gi2 : gi1;
  out[(size_t)row * ACT_DIM + lane] = logits[(size_t)win * ACT_DIM + lane];
}

// ---------------------------------------------------------------------------
extern "C" void kernel_launch(void* const* d_in, const int* in_sizes, int n_in,
                              void* d_out, int out_size, void* d_ws, size_t ws_size,
                              hipStream_t stream) {
  const float* state  = (const float*)d_in[0]; // [2048, 512]
  const float* rp     = (const float*)d_in[1]; // [512, 256]
  const float* mem    = (const float*)d_in[2]; // [16384, 256]
  const float* logits = (const float*)d_in[3]; // [16384, 64]
  float* out = (float*)d_out;                  // [2048, 64]

  // workspace layout (16B-aligned chunks)
  char* ws = (char*)d_ws;
  float*          s       = (float*)ws;                       ws += (size_t)BATCH * PROJ_DIM * 4;   // 2 MB
  unsigned short* s_hi    = (unsigned short*)ws;              ws += (size_t)BATCH * PROJ_DIM * 2;   // 1 MB
  unsigned short* s_mid   = (unsigned short*)ws;              ws += (size_t)BATCH * PROJ_DIM * 2;   // 1 MB
  unsigned short* mem_hi  = (unsigned short*)ws;              ws += (size_t)HEADS * PROJ_DIM * 2;   // 8 MB
  unsigned short* mem_mid = (unsigned short*)ws;              ws += (size_t)HEADS * PROJ_DIM * 2;   // 8 MB
  floatx4*        part    = (floatx4*)ws;                                                           // 4 MB

  split_mem<<<(HEADS * PROJ_DIM) / (256 * 4), 256, 0, stream>>>(mem, mem_hi, mem_mid);

  dim3 g1(BATCH / TILE_M, PROJ_DIM / TILE_N);
  gemm_proj<<<g1, 256, 0, stream>>>(state, rp, s, s_hi, s_mid,
                                    BATCH, PROJ_DIM, FLAT_IN);

  dim3 g2(BATCH / 128, HEADS / 128);   // (16, 128)
  sim_topk<<<g2, 256, 0, stream>>>(s_hi, s_mid, mem_hi, mem_mid, part);

  finalize<<<BATCH, 64, 0, stream>>>(part, s, mem, logits, out);
}

// Round 3
// 207.643 us; speedup vs baseline: 1.7004x; 1.0505x over previous
//
#include <hip/hip_runtime.h>

#define BATCH    2048
#define FLAT_IN  512
#define PROJ_DIM 256
#define HEADS    16384
#define ACT_DIM  64

typedef __attribute__((ext_vector_type(8))) short short8;   // 8 bf16 (4 VGPR)
typedef __attribute__((ext_vector_type(4))) float floatx4;  // MFMA C/D

__device__ __forceinline__ unsigned short f2bf(float x) {
  unsigned u = __float_as_uint(x);
  u += 0x7fff + ((u >> 16) & 1);
  return (unsigned short)(u >> 16);
}
__device__ __forceinline__ float bf2f(unsigned short b) {
  return __uint_as_float(((unsigned)b) << 16);
}

__device__ __forceinline__ void top2_ins(float v, int h, float& b1, int& i1,
                                         float& b2, int& i2) {
  if (v > b1 || (v == b1 && h < i1)) { b2 = b1; i2 = i1; b1 = v; i1 = h; }
  else if (v > b2 || (v == b2 && h < i2)) { b2 = v; i2 = h; }
}

// ---------------------------------------------------------------------------
// Kernel 1: elementwise fp32 -> (bf16 hi, bf16 mid) split. float4 per thread.
// ---------------------------------------------------------------------------
__global__ __launch_bounds__(256) void split_f32(
    const float* __restrict__ in, unsigned short* __restrict__ hi,
    unsigned short* __restrict__ mid)
{
  int i = blockIdx.x * 256 + threadIdx.x;
  float4 v = ((const float4*)in)[i];
  ushort4 h, m;
  h.x = f2bf(v.x); m.x = f2bf(v.x - bf2f(h.x));
  h.y = f2bf(v.y); m.y = f2bf(v.y - bf2f(h.y));
  h.z = f2bf(v.z); m.z = f2bf(v.z - bf2f(h.z));
  h.w = f2bf(v.w); m.w = f2bf(v.w - bf2f(h.w));
  ((ushort4*)hi)[i]  = h;
  ((ushort4*)mid)[i] = m;
}

// ---------------------------------------------------------------------------
// Kernel 2: s = state @ rp via 3-term split-bf16 MFMA; epilogue writes fp32 s
// plus bf16 hi/mid splits of s. Block: 256 rows x 32 cols, 256 thr (4 waves,
// each 64 rows x 32 cols). rp is transposed+split into LDS panel at start.
// ---------------------------------------------------------------------------
__global__ __launch_bounds__(256, 2) void gemm_proj(
    const unsigned short* __restrict__ Ahi, const unsigned short* __restrict__ Amid,
    const float* __restrict__ RP,
    float* __restrict__ S, unsigned short* __restrict__ Shi,
    unsigned short* __restrict__ Smid)
{
  __shared__ __align__(16) unsigned short bp[2][32][512];  // 64KB, XOR-swizzled
  const int tid  = threadIdx.x;
  const int lane = tid & 63, w = tid >> 6;
  const int quad = lane >> 4, col = lane & 15;
  const int m0 = blockIdx.x * 256, n0 = blockIdx.y * 32;

  // --- transpose + split rp cols [n0, n0+32) into LDS, seg swizz = kq ^ c ---
#pragma unroll
  for (int it = 0; it < 8; ++it) {
    int lin = it * 256 + tid;        // 0..2047
    int c   = lin >> 6;              // 0..31 (panel col)
    int kq  = lin & 63;              // 16B k-segment (8 k's)
    int spos = kq ^ c;
    short8 vh, vm;
#pragma unroll
    for (int q = 0; q < 8; ++q) {
      float v = RP[(size_t)(kq * 8 + q) * PROJ_DIM + n0 + c];
      unsigned short hh = f2bf(v);
      vh[q] = (short)hh;
      vm[q] = (short)f2bf(v - bf2f(hh));
    }
    *(short8*)&bp[0][c][spos * 8] = vh;
    *(short8*)&bp[1][c][spos * 8] = vm;
  }
  __syncthreads();

  floatx4 acc[4][2];
#pragma unroll
  for (int i = 0; i < 4; ++i)
#pragma unroll
    for (int j = 0; j < 2; ++j) {
      acc[i][j][0] = 0.f; acc[i][j][1] = 0.f;
      acc[i][j][2] = 0.f; acc[i][j][3] = 0.f;
    }

  const int rowbase = m0 + w * 64;
#pragma unroll
  for (int kc = 0; kc < 16; ++kc) {
    short8 a[4][2];
#pragma unroll
    for (int i = 0; i < 4; ++i) {
      size_t off = (size_t)(rowbase + i * 16 + col) * FLAT_IN + kc * 32 + quad * 8;
      a[i][0] = *(const short8*)(Ahi + off);
      a[i][1] = *(const short8*)(Amid + off);
    }
    short8 b[2][2];
#pragma unroll
    for (int j = 0; j < 2; ++j) {
      int pc = j * 16 + col;
      int spos = (kc * 4 + quad) ^ pc;
      b[j][0] = *(const short8*)&bp[0][pc][spos * 8];
      b[j][1] = *(const short8*)&bp[1][pc][spos * 8];
    }
#pragma unroll
    for (int i = 0; i < 4; ++i)
#pragma unroll
      for (int j = 0; j < 2; ++j) {
        acc[i][j] = __builtin_amdgcn_mfma_f32_16x16x32_bf16(a[i][0], b[j][0], acc[i][j], 0, 0, 0);
        acc[i][j] = __builtin_amdgcn_mfma_f32_16x16x32_bf16(a[i][0], b[j][1], acc[i][j], 0, 0, 0);
        acc[i][j] = __builtin_amdgcn_mfma_f32_16x16x32_bf16(a[i][1], b[j][0], acc[i][j], 0, 0, 0);
      }
  }

#pragma unroll
  for (int i = 0; i < 4; ++i)
#pragma unroll
    for (int j = 0; j < 2; ++j)
#pragma unroll
      for (int r = 0; r < 4; ++r) {
        int row = rowbase + i * 16 + quad * 4 + r;
        int cc  = n0 + j * 16 + col;
        float v = acc[i][j][r];
        S[(size_t)row * PROJ_DIM + cc] = v;
        unsigned short hh = f2bf(v);
        Shi [(size_t)row * PROJ_DIM + cc] = hh;
        Smid[(size_t)row * PROJ_DIM + cc] = f2bf(v - bf2f(hh));
      }
}

// ---------------------------------------------------------------------------
// Kernel 3: sims + per-block per-row top-2. Block = 64 heads (B panel LDS-
// resident, split from fp32 on the fly), 512 thr = 8 waves, wave tile
// 128 rows x 64 heads, A fragments loaded straight from global (L2-hot).
// Zero barriers in the main loop.
// ---------------------------------------------------------------------------
__global__ __launch_bounds__(512, 2) void sim_topk(
    const unsigned short* __restrict__ Ahi, const unsigned short* __restrict__ Amid,
    const float* __restrict__ Mem, float4* __restrict__ partial)
{
  __shared__ __align__(16) unsigned short bp[2][64][256];  // 64KB, swizzled
  const int tid  = threadIdx.x;
  const int lane = tid & 63, w = tid >> 6;
  const int quad = lane >> 4, col = lane & 15;
  const int h0 = blockIdx.x * 64;

  // --- load + split B panel (64 heads x 256 k), seg swizz = s ^ (head&31) ---
#pragma unroll
  for (int it = 0; it < 4; ++it) {
    int lin  = it * 512 + tid;       // 0..2047
    int head = lin >> 5;             // 0..63
    int spos = lin & 31;
    int slog = spos ^ (head & 31);
    const float* g = Mem + (size_t)(h0 + head) * PROJ_DIM + slog * 8;
    short8 vh, vm;
#pragma unroll
    for (int q = 0; q < 8; ++q) {
      float v = g[q];
      unsigned short hh = f2bf(v);
      vh[q] = (short)hh;
      vm[q] = (short)f2bf(v - bf2f(hh));
    }
    *(short8*)&bp[0][head][spos * 8] = vh;
    *(short8*)&bp[1][head][spos * 8] = vm;
  }
  __syncthreads();   // the only barrier

  for (int rc = 0; rc < 2; ++rc) {
    const int rowbase = rc * 1024 + w * 128;
    floatx4 acc[8][4];
#pragma unroll
    for (int i = 0; i < 8; ++i)
#pragma unroll
      for (int j = 0; j < 4; ++j) {
        acc[i][j][0] = 0.f; acc[i][j][1] = 0.f;
        acc[i][j][2] = 0.f; acc[i][j][3] = 0.f;
      }

#pragma unroll
    for (int kc = 0; kc < 8; ++kc) {
      short8 a[8][2];
#pragma unroll
      for (int i = 0; i < 8; ++i) {
        size_t off = (size_t)(rowbase + i * 16 + col) * PROJ_DIM + kc * 32 + quad * 8;
        a[i][0] = *(const short8*)(Ahi + off);
        a[i][1] = *(const short8*)(Amid + off);
      }
      short8 b[4][2];
#pragma unroll
      for (int j = 0; j < 4; ++j) {
        int pc = j * 16 + col;
        int spos = (kc * 4 + quad) ^ (pc & 31);
        b[j][0] = *(const short8*)&bp[0][pc][spos * 8];
        b[j][1] = *(const short8*)&bp[1][pc][spos * 8];
      }
#pragma unroll
      for (int i = 0; i < 8; ++i)
#pragma unroll
        for (int j = 0; j < 4; ++j) {
          acc[i][j] = __builtin_amdgcn_mfma_f32_16x16x32_bf16(a[i][0], b[j][0], acc[i][j], 0, 0, 0);
          acc[i][j] = __builtin_amdgcn_mfma_f32_16x16x32_bf16(a[i][0], b[j][1], acc[i][j], 0, 0, 0);
          acc[i][j] = __builtin_amdgcn_mfma_f32_16x16x32_bf16(a[i][1], b[j][0], acc[i][j], 0, 0, 0);
        }
    }

    // --- epilogue: per-row top-2 over this block's 64 heads ---
#pragma unroll
    for (int i = 0; i < 8; ++i)
#pragma unroll
      for (int r = 0; r < 4; ++r) {
        float b1 = acc[i][0][r]; int h1 = h0 + col;
        float b2 = -3.4e38f;     int h2 = h1;
#pragma unroll
        for (int j = 1; j < 4; ++j) {
          float v = acc[i][j][r]; int h = h0 + j * 16 + col;
          if (v > b1) { b2 = b1; h2 = h1; b1 = v; h1 = h; }
          else if (v > b2) { b2 = v; h2 = h; }
        }
        // merge top-2 across the 16 lanes (cols) of this quad
#pragma unroll
        for (int m = 1; m <= 8; m <<= 1) {
          float ob1 = __shfl_xor(b1, m); int oh1 = __shfl_xor(h1, m);
          float ob2 = __shfl_xor(b2, m); int oh2 = __shfl_xor(h2, m);
          if (ob1 > b1) {
            if (b1 > ob2) { b2 = b1;  h2 = h1;  }
            else          { b2 = ob2; h2 = oh2; }
            b1 = ob1; h1 = oh1;
          } else if (ob1 > b2) { b2 = ob1; h2 = oh1; }
        }
        if (col == 0) {
          int row = rowbase + i * 16 + quad * 4 + r;
          partial[(size_t)row * 256 + blockIdx.x] =
              make_float4(b1, __int_as_float(h1), b2, __int_as_float(h2));
        }
      }
  }
}

// ---------------------------------------------------------------------------
// Kernel 4: merge 256 chunk-partials -> global top-2, exact fp32 rescore,
// gather logits row. One wave per batch row.
// ---------------------------------------------------------------------------
__global__ __launch_bounds__(64) void finalize(
    const float4* __restrict__ partial, const float* __restrict__ S,
    const float* __restrict__ Mem, const float* __restrict__ logits,
    float* __restrict__ out)
{
  const int row  = blockIdx.x;
  const int lane = threadIdx.x;

  float b1 = -3.4e38f, b2 = -3.4e38f; int i1 = 0x7fffffff, i2 = 0x7fffffff;
#pragma unroll
  for (int t = 0; t < 4; ++t) {
    float4 p = partial[(size_t)row * 256 + t * 64 + lane];
    top2_ins(p.x, __float_as_int(p.y), b1, i1, b2, i2);
    top2_ins(p.z, __float_as_int(p.w), b1, i1, b2, i2);
  }

  float g1 = b1; int gi1 = i1;
#pragma unroll
  for (int d = 32; d; d >>= 1) {
    float ov = __shfl_xor(g1, d); int oi = __shfl_xor(gi1, d);
    if (ov > g1 || (ov == g1 && oi < gi1)) { g1 = ov; gi1 = oi; }
  }
  float c  = (i1 == gi1) ? b2 : b1;
  int   ci = (i1 == gi1) ? i2 : i1;
  float g2 = c; int gi2 = ci;
#pragma unroll
  for (int d = 32; d; d >>= 1) {
    float ov = __shfl_xor(g2, d); int oi = __shfl_xor(gi2, d);
    if (ov > g2 || (ov == g2 && oi < gi2)) { g2 = ov; gi2 = oi; }
  }

  float4 sv = ((const float4*)(S   + (size_t)row * PROJ_DIM))[lane];
  float4 m1 = ((const float4*)(Mem + (size_t)gi1 * PROJ_DIM))[lane];
  float4 m2 = ((const float4*)(Mem + (size_t)gi2 * PROJ_DIM))[lane];
  float d1 = sv.x * m1.x + sv.y * m1.y + sv.z * m1.z + sv.w * m1.w;
  float d2 = sv.x * m2.x + sv.y * m2.y + sv.z * m2.z + sv.w * m2.w;
#pragma unroll
  for (int d = 32; d; d >>= 1) {
    d1 += __shfl_xor(d1, d);
    d2 += __shfl_xor(d2, d);
  }
  int win = (d2 > d1 || (d1 == d2 && gi2 < gi1)) ? gi2 : gi1;
  out[(size_t)row * ACT_DIM + lane] = logits[(size_t)win * ACT_DIM + lane];
}

// ---------------------------------------------------------------------------
extern "C" void kernel_launch(void* const* d_in, const int* in_sizes, int n_in,
                              void* d_out, int out_size, void* d_ws, size_t ws_size,
                              hipStream_t stream) {
  const float* state  = (const float*)d_in[0]; // [2048, 512]
  const float* rp     = (const float*)d_in[1]; // [512, 256]
  const float* mem    = (const float*)d_in[2]; // [16384, 256]
  const float* logits = (const float*)d_in[3]; // [16384, 64]
  float* out = (float*)d_out;                  // [2048, 64]

  // workspace (12MB total):
  //   [0,2)MB   s      fp32 [2048][256]
  //   [2,3)MB   s_hi   bf16
  //   [3,4)MB   s_mid  bf16
  //   [4,6)MB   st_hi  bf16 [2048][512]   (dead after gemm_proj)
  //   [6,8)MB   st_mid bf16               (dead after gemm_proj)
  //   [4,12)MB  partial float4 [2048][256] (aliases st_*, written by sim_topk)
  char* ws = (char*)d_ws;
  float*          s      = (float*)ws;
  unsigned short* s_hi   = (unsigned short*)(ws + (2u << 20));
  unsigned short* s_mid  = (unsigned short*)(ws + (3u << 20));
  unsigned short* st_hi  = (unsigned short*)(ws + (4u << 20));
  unsigned short* st_mid = (unsigned short*)(ws + (6u << 20));
  float4*         part   = (float4*)(ws + (4u << 20));

  split_f32<<<BATCH * FLAT_IN / (256 * 4), 256, 0, stream>>>(state, st_hi, st_mid);
  gemm_proj<<<dim3(BATCH / 256, PROJ_DIM / 32), 256, 0, stream>>>(
      st_hi, st_mid, rp, s, s_hi, s_mid);
  sim_topk<<<HEADS / 64, 512, 0, stream>>>(s_hi, s_mid, mem, part);
  finalize<<<BATCH, 64, 0, stream>>>(part, s, mem, logits, out);
}

// Round 4
// 163.700 us; speedup vs baseline: 2.1569x; 1.2684x over previous
//
#include <hip/hip_runtime.h>

#define BATCH    2048
#define FLAT_IN  512
#define PROJ_DIM 256
#define HEADS    16384
#define ACT_DIM  64

typedef __attribute__((ext_vector_type(8))) short short8;   // 8 bf16 (4 VGPR)
typedef __attribute__((ext_vector_type(4))) float floatx4;  // MFMA C/D

__device__ __forceinline__ unsigned short f2bf(float x) {
  unsigned u = __float_as_uint(x);
  u += 0x7fff + ((u >> 16) & 1);
  return (unsigned short)(u >> 16);
}
__device__ __forceinline__ float bf2f(unsigned short b) {
  return __uint_as_float(((unsigned)b) << 16);
}

__device__ __forceinline__ void top2_ins(float v, int h, float& b1, int& i1,
                                         float& b2, int& i2) {
  if (v > b1 || (v == b1 && h < i1)) { b2 = b1; i2 = i1; b1 = v; i1 = h; }
  else if (v > b2 || (v == b2 && h < i2)) { b2 = v; i2 = h; }
}

#define GLDS16(g, l)                                                          \
  __builtin_amdgcn_global_load_lds(                                           \
      (__attribute__((address_space(1))) void*)(void*)(g),                    \
      (__attribute__((address_space(3))) void*)(l), 16, 0, 0)

// ---------------------------------------------------------------------------
// prep: one launch, three jobs partitioned by blockIdx.x
//   [0, 1024)        : split state  [2048][512] fp32 -> st_hi/st_mid bf16
//   [1024, 1056)     : transpose+split rp [512][256] -> rpT_hi/mid [256][512]
//   [1056, 5152)     : split mem [16384][256] fp32 -> mem_hi/mem_mid bf16
// ---------------------------------------------------------------------------
__global__ __launch_bounds__(256) void prep(
    const float* __restrict__ state, const float* __restrict__ rp,
    const float* __restrict__ mem,
    unsigned short* __restrict__ st_hi, unsigned short* __restrict__ st_mid,
    unsigned short* __restrict__ rpT_hi, unsigned short* __restrict__ rpT_mid,
    unsigned short* __restrict__ mem_hi, unsigned short* __restrict__ mem_mid)
{
  const int tid = threadIdx.x;
  const int b = blockIdx.x;
  if (b < 1024 || b >= 1056) {
    const float* in;
    unsigned short *hi, *mid;
    int i;
    if (b < 1024) { in = state; hi = st_hi;  mid = st_mid;  i = b * 256 + tid; }
    else          { in = mem;   hi = mem_hi; mid = mem_mid; i = (b - 1056) * 256 + tid; }
    float4 v = ((const float4*)in)[i];
    ushort4 h, m;
    h.x = f2bf(v.x); m.x = f2bf(v.x - bf2f(h.x));
    h.y = f2bf(v.y); m.y = f2bf(v.y - bf2f(h.y));
    h.z = f2bf(v.z); m.z = f2bf(v.z - bf2f(h.z));
    h.w = f2bf(v.w); m.w = f2bf(v.w - bf2f(h.w));
    ((ushort4*)hi)[i]  = h;
    ((ushort4*)mid)[i] = m;
  } else {
    __shared__ float t[64][65];
    int bid = b - 1024;
    int k0 = (bid >> 2) * 64, n0 = (bid & 3) * 64;
#pragma unroll
    for (int it = 0; it < 16; ++it) {
      int lin = it * 256 + tid;
      int kr = lin >> 6, nc = lin & 63;
      t[kr][nc] = rp[(size_t)(k0 + kr) * PROJ_DIM + n0 + nc];
    }
    __syncthreads();
#pragma unroll
    for (int it = 0; it < 16; ++it) {
      int lin = it * 256 + tid;
      int nr = lin >> 6, kc = lin & 63;
      float v = t[kc][nr];
      unsigned short hh = f2bf(v);
      rpT_hi [(size_t)(n0 + nr) * FLAT_IN + k0 + kc] = hh;
      rpT_mid[(size_t)(n0 + nr) * FLAT_IN + k0 + kc] = f2bf(v - bf2f(hh));
    }
  }
}

// ---------------------------------------------------------------------------
// gemm_proj: s = state @ rp via 3-term split-bf16 MFMA, m97-style staging.
// Tile 64x64, BK=64, grid (32,4)=128 blocks, 256 thr (4 waves, wave 32x32).
// Epilogue writes s (fp32) + s_hi/s_mid (bf16 split).
// ---------------------------------------------------------------------------
__global__ __launch_bounds__(256, 2) void gemm_proj(
    const unsigned short* __restrict__ Ahi, const unsigned short* __restrict__ Amid,
    const unsigned short* __restrict__ Bhi, const unsigned short* __restrict__ Bmid,
    float* __restrict__ S, unsigned short* __restrict__ Shi,
    unsigned short* __restrict__ Smid)
{
  // 4 planes x 64 rows x 64 k bf16 = 4 x 8 KB = 32 KB
  __shared__ __align__(16) unsigned short sm[4][64 * 64];
  const int tid = threadIdx.x;
  const int lane = tid & 63, w = tid >> 6;
  const int quad = lane >> 4, col = lane & 15;
  const int wm = (w >> 1) * 32, wn = (w & 1) * 32;
  const int m0 = blockIdx.x * 64, n0 = blockIdx.y * 64;

  floatx4 acc[2][2];
#pragma unroll
  for (int i = 0; i < 2; ++i)
#pragma unroll
    for (int j = 0; j < 2; ++j) {
      acc[i][j][0] = 0.f; acc[i][j][1] = 0.f;
      acc[i][j][2] = 0.f; acc[i][j][3] = 0.f;
    }

  // staging geometry: 512 granules(16B)/plane; P = issue*256 + tid
  const int P0 = tid, P1 = tid + 256;
  const int r0 = P0 >> 3, kl0 = (P0 & 7) ^ (r0 & 7);
  const int r1 = P1 >> 3, kl1 = (P1 & 7) ^ (r1 & 7);

  for (int kc = 0; kc < FLAT_IN; kc += 64) {
    GLDS16(Ahi  + (size_t)(m0 + r0) * FLAT_IN + kc + kl0 * 8, &sm[0][P0 * 8]);
    GLDS16(Ahi  + (size_t)(m0 + r1) * FLAT_IN + kc + kl1 * 8, &sm[0][P1 * 8]);
    GLDS16(Amid + (size_t)(m0 + r0) * FLAT_IN + kc + kl0 * 8, &sm[1][P0 * 8]);
    GLDS16(Amid + (size_t)(m0 + r1) * FLAT_IN + kc + kl1 * 8, &sm[1][P1 * 8]);
    GLDS16(Bhi  + (size_t)(n0 + r0) * FLAT_IN + kc + kl0 * 8, &sm[2][P0 * 8]);
    GLDS16(Bhi  + (size_t)(n0 + r1) * FLAT_IN + kc + kl1 * 8, &sm[2][P1 * 8]);
    GLDS16(Bmid + (size_t)(n0 + r0) * FLAT_IN + kc + kl0 * 8, &sm[3][P0 * 8]);
    GLDS16(Bmid + (size_t)(n0 + r1) * FLAT_IN + kc + kl1 * 8, &sm[3][P1 * 8]);
    __syncthreads();

#pragma unroll
    for (int ks = 0; ks < 2; ++ks) {
      short8 bf[2][2];
#pragma unroll
      for (int j = 0; j < 2; ++j) {
        int rr = wn + j * 16 + col;
        int off = rr * 64 + (((ks * 4 + quad) ^ (rr & 7)) * 8);
        bf[j][0] = *(const short8*)&sm[2][off];
        bf[j][1] = *(const short8*)&sm[3][off];
      }
#pragma unroll
      for (int i = 0; i < 2; ++i) {
        int rr = wm + i * 16 + col;
        int off = rr * 64 + (((ks * 4 + quad) ^ (rr & 7)) * 8);
        short8 a0 = *(const short8*)&sm[0][off];
        short8 a1 = *(const short8*)&sm[1][off];
#pragma unroll
        for (int j = 0; j < 2; ++j) {
          acc[i][j] = __builtin_amdgcn_mfma_f32_16x16x32_bf16(a0, bf[j][0], acc[i][j], 0, 0, 0);
          acc[i][j] = __builtin_amdgcn_mfma_f32_16x16x32_bf16(a0, bf[j][1], acc[i][j], 0, 0, 0);
          acc[i][j] = __builtin_amdgcn_mfma_f32_16x16x32_bf16(a1, bf[j][0], acc[i][j], 0, 0, 0);
        }
      }
    }
    __syncthreads();
  }

#pragma unroll
  for (int i = 0; i < 2; ++i)
#pragma unroll
    for (int j = 0; j < 2; ++j)
#pragma unroll
      for (int r = 0; r < 4; ++r) {
        int row = m0 + wm + i * 16 + quad * 4 + r;
        int c   = n0 + wn + j * 16 + col;
        float v = acc[i][j][r];
        S[(size_t)row * PROJ_DIM + c] = v;
        unsigned short hh = f2bf(v);
        Shi [(size_t)row * PROJ_DIM + c] = hh;
        Smid[(size_t)row * PROJ_DIM + c] = f2bf(v - bf2f(hh));
      }
}

// ---------------------------------------------------------------------------
// sim_topk: sims = S @ Mem^T via 3-term split-bf16 MFMA, m97-style staging,
// fused per-(row, 128-head-block) top-2.
// Tile 128x128, BK=32, grid (16,128)=2048 blocks, 256 thr (wave tile 64x64).
// partial[row][by] = {v1,h1,v2,h2}
// ---------------------------------------------------------------------------
__global__ __launch_bounds__(256, 2) void sim_topk(
    const unsigned short* __restrict__ Ahi, const unsigned short* __restrict__ Amid,
    const unsigned short* __restrict__ Bhi, const unsigned short* __restrict__ Bmid,
    float4* __restrict__ partial)
{
  // 4 planes x 128 rows x 32 k bf16 = 4 x 8 KB = 32 KB
  __shared__ __align__(16) unsigned short sm[4][128 * 32];
  const int tid = threadIdx.x;
  const int lane = tid & 63, w = tid >> 6;
  const int quad = lane >> 4, col = lane & 15;
  const int wm = (w >> 1) * 64, wn = (w & 1) * 64;
  const int m0 = blockIdx.x * 128;
  const int h0 = blockIdx.y * 128;

  floatx4 acc[4][4];
#pragma unroll
  for (int i = 0; i < 4; ++i)
#pragma unroll
    for (int j = 0; j < 4; ++j) {
      acc[i][j][0] = 0.f; acc[i][j][1] = 0.f;
      acc[i][j][2] = 0.f; acc[i][j][3] = 0.f;
    }

  // staging geometry: 512 granules(16B)/plane; P = issue*256 + tid;
  // row = P>>2, klog = (P&3) ^ (row&3)  (swizzle folded into global index)
  const int P0 = tid, P1 = tid + 256;
  const int r0 = P0 >> 2, kl0 = (P0 & 3) ^ (r0 & 3);
  const int r1 = P1 >> 2, kl1 = (P1 & 3) ^ (r1 & 3);

  for (int kc = 0; kc < PROJ_DIM; kc += 32) {
    GLDS16(Ahi  + (size_t)(m0 + r0) * PROJ_DIM + kc + kl0 * 8, &sm[0][P0 * 8]);
    GLDS16(Ahi  + (size_t)(m0 + r1) * PROJ_DIM + kc + kl1 * 8, &sm[0][P1 * 8]);
    GLDS16(Amid + (size_t)(m0 + r0) * PROJ_DIM + kc + kl0 * 8, &sm[1][P0 * 8]);
    GLDS16(Amid + (size_t)(m0 + r1) * PROJ_DIM + kc + kl1 * 8, &sm[1][P1 * 8]);
    GLDS16(Bhi  + (size_t)(h0 + r0) * PROJ_DIM + kc + kl0 * 8, &sm[2][P0 * 8]);
    GLDS16(Bhi  + (size_t)(h0 + r1) * PROJ_DIM + kc + kl1 * 8, &sm[2][P1 * 8]);
    GLDS16(Bmid + (size_t)(h0 + r0) * PROJ_DIM + kc + kl0 * 8, &sm[3][P0 * 8]);
    GLDS16(Bmid + (size_t)(h0 + r1) * PROJ_DIM + kc + kl1 * 8, &sm[3][P1 * 8]);
    __syncthreads();

    short8 bf[4][2];
#pragma unroll
    for (int j = 0; j < 4; ++j) {
      int rr = wn + j * 16 + col;
      int off = rr * 32 + ((quad ^ (rr & 3)) * 8);
      bf[j][0] = *(const short8*)&sm[2][off];
      bf[j][1] = *(const short8*)&sm[3][off];
    }
#pragma unroll
    for (int i = 0; i < 4; ++i) {
      int rr = wm + i * 16 + col;
      int off = rr * 32 + ((quad ^ (rr & 3)) * 8);
      short8 a0 = *(const short8*)&sm[0][off];
      short8 a1 = *(const short8*)&sm[1][off];
#pragma unroll
      for (int j = 0; j < 4; ++j) {
        acc[i][j] = __builtin_amdgcn_mfma_f32_16x16x32_bf16(a0, bf[j][0], acc[i][j], 0, 0, 0);
        acc[i][j] = __builtin_amdgcn_mfma_f32_16x16x32_bf16(a0, bf[j][1], acc[i][j], 0, 0, 0);
        acc[i][j] = __builtin_amdgcn_mfma_f32_16x16x32_bf16(a1, bf[j][0], acc[i][j], 0, 0, 0);
      }
    }
    __syncthreads();
  }

  // ---- epilogue: per-row top-2 over this block's 128 heads ----
  float4* lds_p = (float4*)&sm[0][0];   // [128][2] float4 = 4 KB (post-barrier reuse)

#pragma unroll
  for (int i = 0; i < 4; ++i)
#pragma unroll
    for (int r = 0; r < 4; ++r) {
      float b1 = acc[i][0][r]; int h1 = h0 + wn + col;
      float b2 = -3.4e38f;     int h2 = h1;
#pragma unroll
      for (int j = 1; j < 4; ++j) {
        float v = acc[i][j][r]; int h = h0 + wn + j * 16 + col;
        if (v > b1) { b2 = b1; h2 = h1; b1 = v; h1 = h; }
        else if (v > b2) { b2 = v; h2 = h; }
      }
#pragma unroll
      for (int m = 1; m <= 8; m <<= 1) {
        float ob1 = __shfl_xor(b1, m); int oh1 = __shfl_xor(h1, m);
        float ob2 = __shfl_xor(b2, m); int oh2 = __shfl_xor(h2, m);
        if (ob1 > b1) {
          if (b1 > ob2) { b2 = b1;  h2 = h1;  }
          else          { b2 = ob2; h2 = oh2; }
          b1 = ob1; h1 = oh1;
        } else if (ob1 > b2) { b2 = ob1; h2 = oh1; }
      }
      if (col == 0) {
        int row = wm + i * 16 + quad * 4 + r;   // 0..127
        lds_p[row * 2 + (w & 1)] =
            make_float4(b1, __int_as_float(h1), b2, __int_as_float(h2));
      }
    }
  __syncthreads();

  if (tid < 128) {
    int row = tid;
    float4 pa = lds_p[row * 2 + 0];
    float4 pb = lds_p[row * 2 + 1];
    float b1 = pa.x; int h1 = __float_as_int(pa.y);
    float b2 = pa.z; int h2 = __float_as_int(pa.w);
    top2_ins(pb.x, __float_as_int(pb.y), b1, h1, b2, h2);
    top2_ins(pb.z, __float_as_int(pb.w), b1, h1, b2, h2);
    partial[(size_t)(m0 + row) * 128 + blockIdx.y] =
        make_float4(b1, __int_as_float(h1), b2, __int_as_float(h2));
  }
}

// ---------------------------------------------------------------------------
// finalize: merge 128 partials/row -> global top-2, exact fp32 rescore of the
// two candidates, gather logits row. One wave per batch row.
// ---------------------------------------------------------------------------
__global__ __launch_bounds__(64) void finalize(
    const float4* __restrict__ partial, const float* __restrict__ S,
    const float* __restrict__ Mem, const float* __restrict__ logits,
    float* __restrict__ out)
{
  const int row  = blockIdx.x;
  const int lane = threadIdx.x;

  float b1 = -3.4e38f, b2 = -3.4e38f; int i1 = 0x7fffffff, i2 = 0x7fffffff;
#pragma unroll
  for (int t = 0; t < 2; ++t) {
    float4 p = partial[(size_t)row * 128 + t * 64 + lane];
    top2_ins(p.x, __float_as_int(p.y), b1, i1, b2, i2);
    top2_ins(p.z, __float_as_int(p.w), b1, i1, b2, i2);
  }

  float g1 = b1; int gi1 = i1;
#pragma unroll
  for (int d = 32; d; d >>= 1) {
    float ov = __shfl_xor(g1, d); int oi = __shfl_xor(gi1, d);
    if (ov > g1 || (ov == g1 && oi < gi1)) { g1 = ov; gi1 = oi; }
  }
  float c  = (i1 == gi1) ? b2 : b1;
  int   ci = (i1 == gi1) ? i2 : i1;
  float g2 = c; int gi2 = ci;
#pragma unroll
  for (int d = 32; d; d >>= 1) {
    float ov = __shfl_xor(g2, d); int oi = __shfl_xor(gi2, d);
    if (ov > g2 || (ov == g2 && oi < gi2)) { g2 = ov; gi2 = oi; }
  }

  float4 sv = ((const float4*)(S   + (size_t)row * PROJ_DIM))[lane];
  float4 m1 = ((const float4*)(Mem + (size_t)gi1 * PROJ_DIM))[lane];
  float4 m2 = ((const float4*)(Mem + (size_t)gi2 * PROJ_DIM))[lane];
  float d1 = sv.x * m1.x + sv.y * m1.y + sv.z * m1.z + sv.w * m1.w;
  float d2 = sv.x * m2.x + sv.y * m2.y + sv.z * m2.z + sv.w * m2.w;
#pragma unroll
  for (int d = 32; d; d >>= 1) {
    d1 += __shfl_xor(d1, d);
    d2 += __shfl_xor(d2, d);
  }
  int win = (d2 > d1 || (d1 == d2 && gi2 < gi1)) ? gi2 : gi1;
  out[(size_t)row * ACT_DIM + lane] = logits[(size_t)win * ACT_DIM + lane];
}

// ---------------------------------------------------------------------------
extern "C" void kernel_launch(void* const* d_in, const int* in_sizes, int n_in,
                              void* d_out, int out_size, void* d_ws, size_t ws_size,
                              hipStream_t stream) {
  const float* state  = (const float*)d_in[0]; // [2048, 512]
  const float* rp     = (const float*)d_in[1]; // [512, 256]
  const float* mem    = (const float*)d_in[2]; // [16384, 256]
  const float* logits = (const float*)d_in[3]; // [16384, 64]
  float* out = (float*)d_out;                  // [2048, 64]

  // workspace layout (28 MB):
  //   [0, 2)M    st_hi  [2048][512] bf16        (dead after gemm_proj)
  //   [2, 4)M    st_mid                         (dead after gemm_proj)
  //   [0, 4)M    partial [2048][128] float4     (overlays st_*, sim_topk out)
  //   [4, 4.25)M rpT_hi [256][512] bf16
  //   [4.25,4.5)M rpT_mid
  //   [8, 16)M   mem_hi [16384][256] bf16
  //   [16,24)M   mem_mid
  //   [24,26)M   s      [2048][256] fp32
  //   [26,27)M   s_hi   bf16
  //   [27,28)M   s_mid  bf16
  char* ws = (char*)d_ws;
  unsigned short* st_hi   = (unsigned short*)(ws);
  unsigned short* st_mid  = (unsigned short*)(ws + (2u  << 20));
  float4*         part    = (float4*)(ws);
  unsigned short* rpT_hi  = (unsigned short*)(ws + (4u  << 20));
  unsigned short* rpT_mid = (unsigned short*)(ws + (4u  << 20) + (256u << 10));
  unsigned short* mem_hi  = (unsigned short*)(ws + (8u  << 20));
  unsigned short* mem_mid = (unsigned short*)(ws + (16u << 20));
  float*          s       = (float*)(ws + (24u << 20));
  unsigned short* s_hi    = (unsigned short*)(ws + (26u << 20));
  unsigned short* s_mid   = (unsigned short*)(ws + (27u << 20));

  prep<<<5152, 256, 0, stream>>>(state, rp, mem, st_hi, st_mid,
                                 rpT_hi, rpT_mid, mem_hi, mem_mid);

  gemm_proj<<<dim3(32, 4), 256, 0, stream>>>(st_hi, st_mid, rpT_hi, rpT_mid,
                                             s, s_hi, s_mid);

  sim_topk<<<dim3(16, 128), 256, 0, stream>>>(s_hi, s_mid, mem_hi, mem_mid, part);

  finalize<<<BATCH, 64, 0, stream>>>(part, s, mem, logits, out);
}

// Round 5
// 139.381 us; speedup vs baseline: 2.5332x; 1.1745x over previous
//
#include <hip/hip_runtime.h>

#define BATCH    2048
#define FLAT_IN  512
#define PROJ_DIM 256
#define HEADS    16384
#define ACT_DIM  64

typedef __attribute__((ext_vector_type(8))) short short8;   // 8 bf16/f16 bits
typedef _Float16 half8 __attribute__((ext_vector_type(8))); // 8 f16 (4 VGPR)
typedef __attribute__((ext_vector_type(4))) float floatx4;  // MFMA C/D

__device__ __forceinline__ unsigned short f2bf(float x) {
  unsigned u = __float_as_uint(x);
  u += 0x7fff + ((u >> 16) & 1);
  return (unsigned short)(u >> 16);
}
__device__ __forceinline__ float bf2f(unsigned short b) {
  return __uint_as_float(((unsigned)b) << 16);
}
__device__ __forceinline__ unsigned short f2h(float x) {
  _Float16 h = (_Float16)x;   // RNE
  return __builtin_bit_cast(unsigned short, h);
}

__device__ __forceinline__ void top2_ins(float v, int h, float& b1, int& i1,
                                         float& b2, int& i2) {
  if (v > b1 || (v == b1 && h < i1)) { b2 = b1; i2 = i1; b1 = v; i1 = h; }
  else if (v > b2 || (v == b2 && h < i2)) { b2 = v; i2 = h; }
}

#define GLDS16(g, l)                                                          \
  __builtin_amdgcn_global_load_lds(                                           \
      (__attribute__((address_space(1))) void*)(void*)(g),                    \
      (__attribute__((address_space(3))) void*)(l), 16, 0, 0)

// ---------------------------------------------------------------------------
// prep: partitioned by blockIdx.x
//   [0, 1024)      : split state [2048][512] -> st_hi/st_mid bf16 (3-term src)
//   [1024, 1056)   : transpose+split rp [512][256] -> rpT_hi/mid [256][512]
//   [1056, 3104)   : mem [16384][256] fp32 -> mem_f16 (single f16 plane)
// ---------------------------------------------------------------------------
__global__ __launch_bounds__(256) void prep(
    const float* __restrict__ state, const float* __restrict__ rp,
    const float* __restrict__ mem,
    unsigned short* __restrict__ st_hi, unsigned short* __restrict__ st_mid,
    unsigned short* __restrict__ rpT_hi, unsigned short* __restrict__ rpT_mid,
    unsigned short* __restrict__ mem_f16)
{
  const int tid = threadIdx.x;
  const int b = blockIdx.x;
  if (b < 1024) {
    int i = b * 256 + tid;
    float4 v = ((const float4*)state)[i];
    ushort4 h, m;
    h.x = f2bf(v.x); m.x = f2bf(v.x - bf2f(h.x));
    h.y = f2bf(v.y); m.y = f2bf(v.y - bf2f(h.y));
    h.z = f2bf(v.z); m.z = f2bf(v.z - bf2f(h.z));
    h.w = f2bf(v.w); m.w = f2bf(v.w - bf2f(h.w));
    ((ushort4*)st_hi)[i]  = h;
    ((ushort4*)st_mid)[i] = m;
  } else if (b < 1056) {
    __shared__ float t[64][65];
    int bid = b - 1024;
    int k0 = (bid >> 2) * 64, n0 = (bid & 3) * 64;
#pragma unroll
    for (int it = 0; it < 16; ++it) {
      int lin = it * 256 + tid;
      int kr = lin >> 6, nc = lin & 63;
      t[kr][nc] = rp[(size_t)(k0 + kr) * PROJ_DIM + n0 + nc];
    }
    __syncthreads();
#pragma unroll
    for (int it = 0; it < 16; ++it) {
      int lin = it * 256 + tid;
      int nr = lin >> 6, kc = lin & 63;
      float v = t[kc][nr];
      unsigned short hh = f2bf(v);
      rpT_hi [(size_t)(n0 + nr) * FLAT_IN + k0 + kc] = hh;
      rpT_mid[(size_t)(n0 + nr) * FLAT_IN + k0 + kc] = f2bf(v - bf2f(hh));
    }
  } else {
    int i2 = (b - 1056) * 256 + tid;          // 8-float granule index
    float4 x = ((const float4*)mem)[2 * i2];
    float4 y = ((const float4*)mem)[2 * i2 + 1];
    short8 o;
    o[0] = (short)f2h(x.x); o[1] = (short)f2h(x.y);
    o[2] = (short)f2h(x.z); o[3] = (short)f2h(x.w);
    o[4] = (short)f2h(y.x); o[5] = (short)f2h(y.y);
    o[6] = (short)f2h(y.z); o[7] = (short)f2h(y.w);
    ((short8*)mem_f16)[i2] = o;
  }
}

// ---------------------------------------------------------------------------
// gemm_proj: s = state @ rp via 3-term split-bf16 MFMA (accuracy-critical;
// rescore depends on s). Tile 64x64, BK=64, grid (32,4), 256 thr.
// Epilogue writes s (fp32) + s_f16.
// ---------------------------------------------------------------------------
__global__ __launch_bounds__(256, 2) void gemm_proj(
    const unsigned short* __restrict__ Ahi, const unsigned short* __restrict__ Amid,
    const unsigned short* __restrict__ Bhi, const unsigned short* __restrict__ Bmid,
    float* __restrict__ S, unsigned short* __restrict__ Sf16)
{
  __shared__ __align__(16) unsigned short sm[4][64 * 64];
  const int tid = threadIdx.x;
  const int lane = tid & 63, w = tid >> 6;
  const int quad = lane >> 4, col = lane & 15;
  const int wm = (w >> 1) * 32, wn = (w & 1) * 32;
  const int m0 = blockIdx.x * 64, n0 = blockIdx.y * 64;

  floatx4 acc[2][2];
#pragma unroll
  for (int i = 0; i < 2; ++i)
#pragma unroll
    for (int j = 0; j < 2; ++j) {
      acc[i][j][0] = 0.f; acc[i][j][1] = 0.f;
      acc[i][j][2] = 0.f; acc[i][j][3] = 0.f;
    }

  const int P0 = tid, P1 = tid + 256;
  const int r0 = P0 >> 3, kl0 = (P0 & 7) ^ (r0 & 7);
  const int r1 = P1 >> 3, kl1 = (P1 & 7) ^ (r1 & 7);

  for (int kc = 0; kc < FLAT_IN; kc += 64) {
    GLDS16(Ahi  + (size_t)(m0 + r0) * FLAT_IN + kc + kl0 * 8, &sm[0][P0 * 8]);
    GLDS16(Ahi  + (size_t)(m0 + r1) * FLAT_IN + kc + kl1 * 8, &sm[0][P1 * 8]);
    GLDS16(Amid + (size_t)(m0 + r0) * FLAT_IN + kc + kl0 * 8, &sm[1][P0 * 8]);
    GLDS16(Amid + (size_t)(m0 + r1) * FLAT_IN + kc + kl1 * 8, &sm[1][P1 * 8]);
    GLDS16(Bhi  + (size_t)(n0 + r0) * FLAT_IN + kc + kl0 * 8, &sm[2][P0 * 8]);
    GLDS16(Bhi  + (size_t)(n0 + r1) * FLAT_IN + kc + kl1 * 8, &sm[2][P1 * 8]);
    GLDS16(Bmid + (size_t)(n0 + r0) * FLAT_IN + kc + kl0 * 8, &sm[3][P0 * 8]);
    GLDS16(Bmid + (size_t)(n0 + r1) * FLAT_IN + kc + kl1 * 8, &sm[3][P1 * 8]);
    __syncthreads();

#pragma unroll
    for (int ks = 0; ks < 2; ++ks) {
      short8 bf[2][2];
#pragma unroll
      for (int j = 0; j < 2; ++j) {
        int rr = wn + j * 16 + col;
        int off = rr * 64 + (((ks * 4 + quad) ^ (rr & 7)) * 8);
        bf[j][0] = *(const short8*)&sm[2][off];
        bf[j][1] = *(const short8*)&sm[3][off];
      }
#pragma unroll
      for (int i = 0; i < 2; ++i) {
        int rr = wm + i * 16 + col;
        int off = rr * 64 + (((ks * 4 + quad) ^ (rr & 7)) * 8);
        short8 a0 = *(const short8*)&sm[0][off];
        short8 a1 = *(const short8*)&sm[1][off];
#pragma unroll
        for (int j = 0; j < 2; ++j) {
          acc[i][j] = __builtin_amdgcn_mfma_f32_16x16x32_bf16(a0, bf[j][0], acc[i][j], 0, 0, 0);
          acc[i][j] = __builtin_amdgcn_mfma_f32_16x16x32_bf16(a0, bf[j][1], acc[i][j], 0, 0, 0);
          acc[i][j] = __builtin_amdgcn_mfma_f32_16x16x32_bf16(a1, bf[j][0], acc[i][j], 0, 0, 0);
        }
      }
    }
    __syncthreads();
  }

#pragma unroll
  for (int i = 0; i < 2; ++i)
#pragma unroll
    for (int j = 0; j < 2; ++j)
#pragma unroll
      for (int r = 0; r < 4; ++r) {
        int row = m0 + wm + i * 16 + quad * 4 + r;
        int c   = n0 + wn + j * 16 + col;
        float v = acc[i][j][r];
        S   [(size_t)row * PROJ_DIM + c] = v;
        Sf16[(size_t)row * PROJ_DIM + c] = f2h(v);
      }
}

// ---------------------------------------------------------------------------
// sim_topk: sims = s_f16 @ mem_f16^T, single fp16 MFMA term, fused per-row
// top-2 per block. Tile 128x256, BK=64, grid (16,64), 512 thr (8 waves,
// wave tile 64x64, wave grid 2x4). partial[row][by] = {v1,h1,v2,h2}.
// ---------------------------------------------------------------------------
__global__ __launch_bounds__(512, 4) void sim_topk(
    const unsigned short* __restrict__ Af16,   // [2048][256]
    const unsigned short* __restrict__ Bf16,   // [16384][256]
    float4* __restrict__ partial)
{
  __shared__ __align__(16) unsigned short smA[128 * 64];  // 16 KB
  __shared__ __align__(16) unsigned short smB[256 * 64];  // 32 KB
  const int tid = threadIdx.x;
  const int lane = tid & 63, w = tid >> 6;
  const int quad = lane >> 4, col = lane & 15;
  const int wm = (w >> 2) * 64, wn = (w & 3) * 64;
  const int m0 = blockIdx.x * 128;
  const int h0 = blockIdx.y * 256;

  floatx4 acc[4][4];
#pragma unroll
  for (int i = 0; i < 4; ++i)
#pragma unroll
    for (int j = 0; j < 4; ++j) {
      acc[i][j][0] = 0.f; acc[i][j][1] = 0.f;
      acc[i][j][2] = 0.f; acc[i][j][3] = 0.f;
    }

  // staging geometry. A: 1024 granules (2 issues), B: 2048 granules (4 issues)
  // granule P: row = P>>3, phys k-slot = P&7, logical k = (P&7)^(row&7)
  const int PA0 = tid, PA1 = tid + 512;
  const int ra0 = PA0 >> 3, ka0 = (PA0 & 7) ^ (ra0 & 7);
  const int ra1 = PA1 >> 3, ka1 = (PA1 & 7) ^ (ra1 & 7);
  int rb[4], kb[4];
#pragma unroll
  for (int t = 0; t < 4; ++t) {
    int P = t * 512 + tid;
    rb[t] = P >> 3; kb[t] = (P & 7) ^ (rb[t] & 7);
  }

  for (int kc = 0; kc < PROJ_DIM; kc += 64) {
    GLDS16(Af16 + (size_t)(m0 + ra0) * PROJ_DIM + kc + ka0 * 8, &smA[PA0 * 8]);
    GLDS16(Af16 + (size_t)(m0 + ra1) * PROJ_DIM + kc + ka1 * 8, &smA[PA1 * 8]);
#pragma unroll
    for (int t = 0; t < 4; ++t) {
      GLDS16(Bf16 + (size_t)(h0 + rb[t]) * PROJ_DIM + kc + kb[t] * 8,
             &smB[(t * 512 + tid) * 8]);
    }
    __syncthreads();

#pragma unroll
    for (int ks = 0; ks < 2; ++ks) {
      half8 a[4], bfr[4];
#pragma unroll
      for (int i = 0; i < 4; ++i) {
        int rr = wm + i * 16 + col;
        int off = rr * 64 + (((ks * 4 + quad) ^ (rr & 7)) * 8);
        a[i] = *(const half8*)&smA[off];
      }
#pragma unroll
      for (int j = 0; j < 4; ++j) {
        int rr = wn + j * 16 + col;
        int off = rr * 64 + (((ks * 4 + quad) ^ (rr & 7)) * 8);
        bfr[j] = *(const half8*)&smB[off];
      }
#pragma unroll
      for (int i = 0; i < 4; ++i)
#pragma unroll
        for (int j = 0; j < 4; ++j)
          acc[i][j] = __builtin_amdgcn_mfma_f32_16x16x32_f16(a[i], bfr[j], acc[i][j], 0, 0, 0);
    }
    __syncthreads();
  }

  // ---- epilogue: per-row top-2 over this block's 256 heads ----
  float4* lds_p = (float4*)smA;   // [128][4] float4 = 8 KB (LDS free post-barrier)

#pragma unroll
  for (int i = 0; i < 4; ++i)
#pragma unroll
    for (int r = 0; r < 4; ++r) {
      float b1 = acc[i][0][r]; int h1 = h0 + wn + col;
      float b2 = -3.4e38f;     int h2 = h1;
#pragma unroll
      for (int j = 1; j < 4; ++j) {
        float v = acc[i][j][r]; int h = h0 + wn + j * 16 + col;
        if (v > b1) { b2 = b1; h2 = h1; b1 = v; h1 = h; }
        else if (v > b2) { b2 = v; h2 = h; }
      }
#pragma unroll
      for (int m = 1; m <= 8; m <<= 1) {
        float ob1 = __shfl_xor(b1, m); int oh1 = __shfl_xor(h1, m);
        float ob2 = __shfl_xor(b2, m); int oh2 = __shfl_xor(h2, m);
        if (ob1 > b1) {
          if (b1 > ob2) { b2 = b1;  h2 = h1;  }
          else          { b2 = ob2; h2 = oh2; }
          b1 = ob1; h1 = oh1;
        } else if (ob1 > b2) { b2 = ob1; h2 = oh1; }
      }
      if (col == 0) {
        int row = wm + i * 16 + quad * 4 + r;   // 0..127
        lds_p[row * 4 + (w & 3)] =
            make_float4(b1, __int_as_float(h1), b2, __int_as_float(h2));
      }
    }
  __syncthreads();

  if (tid < 128) {
    int row = tid;
    float b1 = -3.4e38f, b2 = -3.4e38f; int h1 = 0x7fffffff, h2 = 0x7fffffff;
#pragma unroll
    for (int t = 0; t < 4; ++t) {
      float4 p = lds_p[row * 4 + t];
      top2_ins(p.x, __float_as_int(p.y), b1, h1, b2, h2);
      top2_ins(p.z, __float_as_int(p.w), b1, h1, b2, h2);
    }
    partial[(size_t)(m0 + row) * 64 + blockIdx.y] =
        make_float4(b1, __int_as_float(h1), b2, __int_as_float(h2));
  }
}

// ---------------------------------------------------------------------------
// finalize: merge 64 partials/row (128 candidates) -> global top-4, exact
// fp32 rescore of all 4, pick winner, gather logits row. 1 wave per row.
// ---------------------------------------------------------------------------
__global__ __launch_bounds__(64) void finalize(
    const float4* __restrict__ partial, const float* __restrict__ S,
    const float* __restrict__ Mem, const float* __restrict__ logits,
    float* __restrict__ out)
{
  const int row  = blockIdx.x;
  const int lane = threadIdx.x;

  float4 p = partial[(size_t)row * 64 + lane];
  float v0 = p.x; int c0 = __float_as_int(p.y);
  float v1 = p.z; int c1 = __float_as_int(p.w);

  int cand[4];
#pragma unroll
  for (int t = 0; t < 4; ++t) {
    float lv; int lh;
    if (v0 > v1 || (v0 == v1 && c0 < c1)) { lv = v0; lh = c0; }
    else                                  { lv = v1; lh = c1; }
#pragma unroll
    for (int d = 32; d; d >>= 1) {
      float ov = __shfl_xor(lv, d); int oh = __shfl_xor(lh, d);
      if (ov > lv || (ov == lv && oh < lh)) { lv = ov; lh = oh; }
    }
    cand[t] = lh;
    if (c0 == lh) v0 = -3.4e38f;
    if (c1 == lh) v1 = -3.4e38f;
  }

  // exact fp32 rescore of the 4 candidates (lane owns 4 k's)
  float4 sv = ((const float4*)(S + (size_t)row * PROJ_DIM))[lane];
  float bestv = -3.4e38f; int besth = 0x7fffffff;
#pragma unroll
  for (int t = 0; t < 4; ++t) {
    float4 mv = ((const float4*)(Mem + (size_t)cand[t] * PROJ_DIM))[lane];
    float d = sv.x * mv.x + sv.y * mv.y + sv.z * mv.z + sv.w * mv.w;
#pragma unroll
    for (int s = 32; s; s >>= 1) d += __shfl_xor(d, s);
    if (d > bestv || (d == bestv && cand[t] < besth)) { bestv = d; besth = cand[t]; }
  }
  out[(size_t)row * ACT_DIM + lane] = logits[(size_t)besth * ACT_DIM + lane];
}

// ---------------------------------------------------------------------------
extern "C" void kernel_launch(void* const* d_in, const int* in_sizes, int n_in,
                              void* d_out, int out_size, void* d_ws, size_t ws_size,
                              hipStream_t stream) {
  const float* state  = (const float*)d_in[0]; // [2048, 512]
  const float* rp     = (const float*)d_in[1]; // [512, 256]
  const float* mem    = (const float*)d_in[2]; // [16384, 256]
  const float* logits = (const float*)d_in[3]; // [16384, 64]
  float* out = (float*)d_out;                  // [2048, 64]

  // workspace layout (22 MB):
  //   [0, 2)M    st_hi  [2048][512] bf16
  //   [2, 4)M    st_mid
  //   [4, 4.25)M rpT_hi [256][512] bf16
  //   [4.25,4.5)M rpT_mid
  //   [8, 16)M   mem_f16 [16384][256] f16
  //   [16,18)M   s      [2048][256] fp32
  //   [18,19)M   s_f16  [2048][256] f16
  //   [20,22)M   partial [2048][64] float4
  char* ws = (char*)d_ws;
  unsigned short* st_hi   = (unsigned short*)(ws);
  unsigned short* st_mid  = (unsigned short*)(ws + (2u  << 20));
  unsigned short* rpT_hi  = (unsigned short*)(ws + (4u  << 20));
  unsigned short* rpT_mid = (unsigned short*)(ws + (4u  << 20) + (256u << 10));
  unsigned short* mem_f16 = (unsigned short*)(ws + (8u  << 20));
  float*          s       = (float*)(ws + (16u << 20));
  unsigned short* s_f16   = (unsigned short*)(ws + (18u << 20));
  float4*         part    = (float4*)(ws + (20u << 20));

  prep<<<3104, 256, 0, stream>>>(state, rp, mem, st_hi, st_mid,
                                 rpT_hi, rpT_mid, mem_f16);

  gemm_proj<<<dim3(32, 4), 256, 0, stream>>>(st_hi, st_mid, rpT_hi, rpT_mid,
                                             s, s_f16);

  sim_topk<<<dim3(16, 64), 512, 0, stream>>>(s_f16, mem_f16, part);

  finalize<<<BATCH, 64, 0, stream>>>(part, s, mem, logits, out);
}